// Round 3
// baseline (18314.998 us; speedup 1.0000x reference)
//
#include <hip/hip_runtime.h>
#include <hip/hip_bf16.h>

// Problem constants
#define TT 256
#define NENVS 64
#define AG 16
#define ROWS (NENVS * AG)   // 1024
#define NIN 12
#define NEMB 64
#define NEDGE 128
#define NRNN 128
#define NOUT 256
#define NGI (3 * NRNN)      // 384

// Output layout (f32): out [T][ROWS][256] then h_last [ROWS][128]
#define OUT_ELEMS ((size_t)TT * ROWS * NOUT)   // 67,108,864

// gi slot layout (within each 1024B output row slot):
//   [0,512):   256 bf16 = gi_r[0:128] | gi_z[0:128]
//   [512,1024): 128 f32 = gi_n[0:128]
// K2 reads gi then overwrites the slot with out[t,row] (f32, 1024B).

// ---------------------------------------------------------------------------
// K1: per (t,row): enc = relu(W_enc@pos+b), emb = relu(W_edge@[ht|hs]+b),
//     x = [enc|emb], gi = W_ih@x + b_ih  -> stored into d_out row slot.
// ---------------------------------------------------------------------------
__global__ __launch_bounds__(256) void k_gi(
    const float* __restrict__ pos, const float* __restrict__ ht,
    const float* __restrict__ hs,
    const float* __restrict__ W_enc, const float* __restrict__ b_enc,
    const float* __restrict__ W_edge, const float* __restrict__ b_edge,
    const float* __restrict__ W_ih, const float* __restrict__ b_ih,
    char* __restrict__ out_base)
{
    __shared__ float sh_edges[4][256];
    __shared__ float sh_x[4][128];
    __shared__ float sh_pos[4][16];

    const int w = threadIdx.x >> 6;     // wave id in block (0..3)
    const int lane = threadIdx.x & 63;
    const size_t task = (size_t)blockIdx.x * 4 + w;   // t*1024 + r, < 262144

    // ---- stage edges (256 f32) and pos (12 f32) into LDS ----
    const float* htp = ht + task * 128;
    const float* hsp = hs + task * 128;
    if (lane < 32) {
        float4 v = *(const float4*)(htp + lane * 4);
        *(float4*)&sh_edges[w][lane * 4] = v;
    } else {
        float4 v = *(const float4*)(hsp + (lane - 32) * 4);
        *(float4*)&sh_edges[w][128 + (lane - 32) * 4] = v;
    }
    if (lane < NIN) sh_pos[w][lane] = pos[task * NIN + lane];
    __syncthreads();

    // ---- enc: one output per lane ----
    {
        float s = b_enc[lane];
        #pragma unroll
        for (int d = 0; d < NIN; ++d)
            s = fmaf(W_enc[lane * NIN + d], sh_pos[w][d], s);
        sh_x[w][lane] = fmaxf(s, 0.0f);
    }
    // ---- emb: one output per lane, 256-dot ----
    {
        float s = b_edge[lane];
        const float4* wrow = (const float4*)(W_edge + (size_t)lane * 256);
        const float4* e4 = (const float4*)sh_edges[w];
        #pragma unroll 8
        for (int d4 = 0; d4 < 64; ++d4) {
            float4 wv = wrow[d4];
            float4 ev = e4[d4];
            s = fmaf(wv.x, ev.x, s); s = fmaf(wv.y, ev.y, s);
            s = fmaf(wv.z, ev.z, s); s = fmaf(wv.w, ev.w, s);
        }
        sh_x[w][64 + lane] = fmaxf(s, 0.0f);
    }
    __syncthreads();

    // ---- gi: 6 outputs per lane (o = lane + 64j), 128-dot from LDS x ----
    char* slot = out_base + task * 1024;
    __hip_bfloat16* g_rz = (__hip_bfloat16*)slot;        // o in [0,256)
    float* g_n = (float*)(slot + 512);                   // o in [256,384)
    const float4* x4 = (const float4*)sh_x[w];
    #pragma unroll
    for (int j = 0; j < 6; ++j) {
        const int o = lane + 64 * j;
        float s = b_ih[o];
        const float4* wrow = (const float4*)(W_ih + (size_t)o * 128);
        #pragma unroll 8
        for (int k4 = 0; k4 < 32; ++k4) {
            float4 wv = wrow[k4];
            float4 xv = x4[k4];
            s = fmaf(wv.x, xv.x, s); s = fmaf(wv.y, xv.y, s);
            s = fmaf(wv.z, xv.z, s); s = fmaf(wv.w, xv.w, s);
        }
        if (o < 256) g_rz[o] = __float2bfloat16(s);
        else         g_n[o - 256] = s;
    }
}

// ---------------------------------------------------------------------------
// K2: sequential GRU scan. 4 rows per block (256 blocks x 256 threads) so
// the 4 row-groups' reads of the same weight rows hit L1 -> 4x less L2
// traffic than 1 row/block. h kept in LDS (f32). Fused output projection
// overwrites the gi slot after gi is consumed.
// ---------------------------------------------------------------------------
__global__ __launch_bounds__(256) void k_scan(
    const float* __restrict__ h0, const float* __restrict__ masks,
    const float* __restrict__ W_hh, const float* __restrict__ b_hh,
    const float* __restrict__ W_out, const float* __restrict__ b_out,
    float* __restrict__ dout)
{
    const int row  = threadIdx.x >> 6;   // 0..3 (row group)
    const int lane = threadIdx.x & 63;
    const int r = blockIdx.x * 4 + row;  // global row 0..1023
    const int n_env = r >> 4;

    __shared__ float h_lds[4][128];
    h_lds[row][lane]      = h0[(size_t)r * 128 + lane];
    h_lds[row][lane + 64] = h0[(size_t)r * 128 + lane + 64];

    const char* obase = (const char*)dout;
    float hnew0 = 0.0f, hnew1 = 0.0f;

    // bias preload (invariant)
    float bh[6];
    #pragma unroll
    for (int j = 0; j < 6; ++j) bh[j] = b_hh[lane + 64 * j];
    float bo[4];
    #pragma unroll
    for (int j = 0; j < 4; ++j) bo[j] = b_out[lane + 64 * j];

    for (int t = 0; t < TT; ++t) {
        __syncthreads();            // S1: prev-step out-proj reads of h done
        const float m = masks[t * NENVS + n_env];
        const float hold0 = h_lds[row][lane] * m;
        const float hold1 = h_lds[row][lane + 64] * m;
        h_lds[row][lane] = hold0;
        h_lds[row][lane + 64] = hold1;

        // issue gi loads EARLY so global latency hides under the gh FMA loop
        const char* slot = obase + ((size_t)t * ROWS + r) * 1024;
        const __hip_bfloat16* g_rz = (const __hip_bfloat16*)slot;
        const float* g_n = (const float*)(slot + 512);
        const float gir0 = __bfloat162float(g_rz[lane]);
        const float gir1 = __bfloat162float(g_rz[lane + 64]);
        const float giz0 = __bfloat162float(g_rz[128 + lane]);
        const float giz1 = __bfloat162float(g_rz[128 + lane + 64]);
        const float gin0 = g_n[lane];
        const float gin1 = g_n[lane + 64];

        __syncthreads();            // S2: masked h visible to all

        // gh: 6 outputs o = lane + 64j, dot over h_lds[row][0..128)
        float acc[6];
        #pragma unroll
        for (int j = 0; j < 6; ++j) acc[j] = bh[j];
        {
            const float4* h4 = (const float4*)h_lds[row];
            const float4* w0 = (const float4*)(W_hh + (size_t)(lane)        * 128);
            const float4* w1 = (const float4*)(W_hh + (size_t)(lane + 64)   * 128);
            const float4* w2 = (const float4*)(W_hh + (size_t)(lane + 128)  * 128);
            const float4* w3 = (const float4*)(W_hh + (size_t)(lane + 192)  * 128);
            const float4* w4 = (const float4*)(W_hh + (size_t)(lane + 256)  * 128);
            const float4* w5 = (const float4*)(W_hh + (size_t)(lane + 320)  * 128);
            #pragma unroll 8
            for (int k4 = 0; k4 < 32; ++k4) {
                const float4 hv = h4[k4];
                float4 wv;
                wv = w0[k4];
                acc[0] = fmaf(wv.x, hv.x, acc[0]); acc[0] = fmaf(wv.y, hv.y, acc[0]);
                acc[0] = fmaf(wv.z, hv.z, acc[0]); acc[0] = fmaf(wv.w, hv.w, acc[0]);
                wv = w1[k4];
                acc[1] = fmaf(wv.x, hv.x, acc[1]); acc[1] = fmaf(wv.y, hv.y, acc[1]);
                acc[1] = fmaf(wv.z, hv.z, acc[1]); acc[1] = fmaf(wv.w, hv.w, acc[1]);
                wv = w2[k4];
                acc[2] = fmaf(wv.x, hv.x, acc[2]); acc[2] = fmaf(wv.y, hv.y, acc[2]);
                acc[2] = fmaf(wv.z, hv.z, acc[2]); acc[2] = fmaf(wv.w, hv.w, acc[2]);
                wv = w3[k4];
                acc[3] = fmaf(wv.x, hv.x, acc[3]); acc[3] = fmaf(wv.y, hv.y, acc[3]);
                acc[3] = fmaf(wv.z, hv.z, acc[3]); acc[3] = fmaf(wv.w, hv.w, acc[3]);
                wv = w4[k4];
                acc[4] = fmaf(wv.x, hv.x, acc[4]); acc[4] = fmaf(wv.y, hv.y, acc[4]);
                acc[4] = fmaf(wv.z, hv.z, acc[4]); acc[4] = fmaf(wv.w, hv.w, acc[4]);
                wv = w5[k4];
                acc[5] = fmaf(wv.x, hv.x, acc[5]); acc[5] = fmaf(wv.y, hv.y, acc[5]);
                acc[5] = fmaf(wv.z, hv.z, acc[5]); acc[5] = fmaf(wv.w, hv.w, acc[5]);
            }
        }

        // pointwise GRU update: k0 = lane (acc 0,2,4), k1 = lane+64 (acc 1,3,5)
        const float rr0 = 1.0f / (1.0f + __expf(-(gir0 + acc[0])));
        const float zz0 = 1.0f / (1.0f + __expf(-(giz0 + acc[2])));
        const float nn0 = tanhf(gin0 + rr0 * acc[4]);
        hnew0 = (1.0f - zz0) * nn0 + zz0 * hold0;
        const float rr1 = 1.0f / (1.0f + __expf(-(gir1 + acc[1])));
        const float zz1 = 1.0f / (1.0f + __expf(-(giz1 + acc[3])));
        const float nn1 = tanhf(gin1 + rr1 * acc[5]);
        hnew1 = (1.0f - zz1) * nn1 + zz1 * hold1;

        __syncthreads();            // S3: all gh dots + gi reads done
        h_lds[row][lane] = hnew0;
        h_lds[row][lane + 64] = hnew1;
        __syncthreads();            // S4: h_new visible

        // fused output projection: o = lane + 64j, j=0..3 (overwrites gi slot)
        float* orow = dout + ((size_t)t * ROWS + r) * NOUT;
        {
            const float4* h4 = (const float4*)h_lds[row];
            float so[4];
            #pragma unroll
            for (int j = 0; j < 4; ++j) so[j] = bo[j];
            const float4* o0 = (const float4*)(W_out + (size_t)(lane)       * 128);
            const float4* o1 = (const float4*)(W_out + (size_t)(lane + 64)  * 128);
            const float4* o2 = (const float4*)(W_out + (size_t)(lane + 128) * 128);
            const float4* o3 = (const float4*)(W_out + (size_t)(lane + 192) * 128);
            #pragma unroll 8
            for (int k4 = 0; k4 < 32; ++k4) {
                const float4 hv = h4[k4];
                float4 wv;
                wv = o0[k4];
                so[0] = fmaf(wv.x, hv.x, so[0]); so[0] = fmaf(wv.y, hv.y, so[0]);
                so[0] = fmaf(wv.z, hv.z, so[0]); so[0] = fmaf(wv.w, hv.w, so[0]);
                wv = o1[k4];
                so[1] = fmaf(wv.x, hv.x, so[1]); so[1] = fmaf(wv.y, hv.y, so[1]);
                so[1] = fmaf(wv.z, hv.z, so[1]); so[1] = fmaf(wv.w, hv.w, so[1]);
                wv = o2[k4];
                so[2] = fmaf(wv.x, hv.x, so[2]); so[2] = fmaf(wv.y, hv.y, so[2]);
                so[2] = fmaf(wv.z, hv.z, so[2]); so[2] = fmaf(wv.w, hv.w, so[2]);
                wv = o3[k4];
                so[3] = fmaf(wv.x, hv.x, so[3]); so[3] = fmaf(wv.y, hv.y, so[3]);
                so[3] = fmaf(wv.z, hv.z, so[3]); so[3] = fmaf(wv.w, hv.w, so[3]);
            }
            #pragma unroll
            for (int j = 0; j < 4; ++j) orow[lane + 64 * j] = so[j];
        }
    }

    // h_last (f32) after the out block
    dout[OUT_ELEMS + (size_t)r * 128 + lane] = hnew0;
    dout[OUT_ELEMS + (size_t)r * 128 + lane + 64] = hnew1;
}

extern "C" void kernel_launch(void* const* d_in, const int* in_sizes, int n_in,
                              void* d_out, int out_size, void* d_ws, size_t ws_size,
                              hipStream_t stream) {
    const float* pos    = (const float*)d_in[0];
    const float* ht     = (const float*)d_in[1];
    const float* hs     = (const float*)d_in[2];
    const float* h0     = (const float*)d_in[3];
    const float* masks  = (const float*)d_in[4];
    const float* W_enc  = (const float*)d_in[5];
    const float* b_enc  = (const float*)d_in[6];
    const float* W_edge = (const float*)d_in[7];
    const float* b_edge = (const float*)d_in[8];
    const float* W_ih   = (const float*)d_in[9];
    const float* b_ih   = (const float*)d_in[10];
    const float* W_hh   = (const float*)d_in[11];
    const float* b_hh   = (const float*)d_in[12];
    const float* W_out  = (const float*)d_in[13];
    const float* b_out  = (const float*)d_in[14];
    float* out = (float*)d_out;

    // K1: 262144 (t,row) tasks, 4 per block (one wave each)
    hipLaunchKernelGGL(k_gi, dim3((TT * ROWS) / 4), dim3(256), 0, stream,
                       pos, ht, hs, W_enc, b_enc, W_edge, b_edge, W_ih, b_ih,
                       (char*)d_out);
    // K2: 4 rows per block
    hipLaunchKernelGGL(k_scan, dim3(ROWS / 4), dim3(256), 0, stream,
                       h0, masks, W_hh, b_hh, W_out, b_out, out);
}

// Round 4
// 1008.220 us; speedup vs baseline: 18.1657x; 18.1657x over previous
//
#include <hip/hip_runtime.h>
#include <hip/hip_bf16.h>
#include <stdint.h>

#define TT 256
#define ROWSG 1024
#define OUT_ELEMS ((size_t)TT * ROWSG * 256)   // 67,108,864 f32

// Superslot layout per (t, rtile16): 16 consecutive 1KB out-row slots = 16KB:
//   [0,12288):     gi frags, 24 nt x 64 lanes x 4 bf16 (8B)  [written k_gi, read k_scan]
//   [12288,16384): x bf16 row-major [16][128]                [written k_embed, read k_gi]
//                  then ys bf16 col-major [128][16]          [written k_scan, read k_out]
//   k_out overwrites the whole superslot with out f32 [16][256].

typedef __attribute__((ext_vector_type(8))) short bf16x8;
typedef __attribute__((ext_vector_type(4))) float f32x4;

__device__ __forceinline__ uint32_t bfbits(float f) {
    uint32_t u = __float_as_uint(f);
    return (u + 0x7fffu + ((u >> 16) & 1u)) >> 16;   // RNE f32->bf16
}
__device__ __forceinline__ float bf2f(uint32_t b16) {
    return __uint_as_float(b16 << 16);
}
__device__ __forceinline__ uint32_t pack2(float a, float b) {
    return bfbits(a) | (bfbits(b) << 16);
}
// 8 consecutive f32 (16B aligned) -> bf16x8
__device__ __forceinline__ bf16x8 ld8cvt(const float* p) {
    float4 f0 = *(const float4*)p;
    float4 f1 = *(const float4*)(p + 4);
    bf16x8 r;
    r[0] = (short)bfbits(f0.x); r[1] = (short)bfbits(f0.y);
    r[2] = (short)bfbits(f0.z); r[3] = (short)bfbits(f0.w);
    r[4] = (short)bfbits(f1.x); r[5] = (short)bfbits(f1.y);
    r[6] = (short)bfbits(f1.z); r[7] = (short)bfbits(f1.w);
    return r;
}

// ---------------------------------------------------------------------------
// K1a: enc = relu(pos@W_encT+b), emb = relu([ht|hs]@W_edgeT+b) -> x bf16.
// 512 blocks x 256 thr; each block 8 chunks of 64 rows (wave = 16-row tile).
// W_edge (32 frags) + W_enc (4 frags) in registers per wave.
// ---------------------------------------------------------------------------
__global__ __launch_bounds__(256, 2) void k_embed(
    const float* __restrict__ pos, const float* __restrict__ ht,
    const float* __restrict__ hs,
    const float* __restrict__ W_enc, const float* __restrict__ b_enc,
    const float* __restrict__ W_edge, const float* __restrict__ b_edge,
    char* __restrict__ obase)
{
    const int tid = threadIdx.x;
    const int w = tid >> 6, lane = tid & 63;
    const int lr = lane & 15, lq = lane >> 4;

    __shared__ __align__(16) short xbuf[4][2048];  // per-wave 16x128 bf16

    // --- W_enc B-frags (K=12 zero-padded to 32), 4 n-tiles ---
    bf16x8 Wenc[4];
    float benc[4];
    #pragma unroll
    for (int nt = 0; nt < 4; ++nt) {
        const int o = nt * 16 + lr;
        benc[nt] = b_enc[o];
        float v[8];
        #pragma unroll
        for (int j = 0; j < 8; ++j) v[j] = 0.f;
        const float* p = W_enc + o * 12;
        if (lq == 0) {
            float4 a = *(const float4*)p;
            float4 b = *(const float4*)(p + 4);
            v[0]=a.x; v[1]=a.y; v[2]=a.z; v[3]=a.w;
            v[4]=b.x; v[5]=b.y; v[6]=b.z; v[7]=b.w;
        } else if (lq == 1) {
            float4 a = *(const float4*)(p + 8);
            v[0]=a.x; v[1]=a.y; v[2]=a.z; v[3]=a.w;  // k=8..11, rest 0
        }
        bf16x8 f;
        #pragma unroll
        for (int j = 0; j < 8; ++j) f[j] = (short)bfbits(v[j]);
        Wenc[nt] = f;
    }
    // --- W_edge B-frags: [kt 0..7][nt 0..3] ---
    bf16x8 Wedge[8][4];
    float bedge[4];
    #pragma unroll
    for (int nt = 0; nt < 4; ++nt) {
        const int o = nt * 16 + lr;
        bedge[nt] = b_edge[o];
        #pragma unroll
        for (int kt = 0; kt < 8; ++kt)
            Wedge[kt][nt] = ld8cvt(W_edge + (size_t)o * 256 + kt * 32 + lq * 8);
    }

    for (int chunk = 0; chunk < 8; ++chunk) {
        const size_t F0 = (size_t)blockIdx.x * 512 + chunk * 64 + w * 16;
        const size_t row = F0 + lr;

        // enc MFMA (A = pos zero-padded)
        bf16x8 Apos;
        {
            float v[8];
            #pragma unroll
            for (int j = 0; j < 8; ++j) v[j] = 0.f;
            const float* p = pos + row * 12;
            if (lq == 0) {
                float4 a = *(const float4*)p;
                float4 b = *(const float4*)(p + 4);
                v[0]=a.x; v[1]=a.y; v[2]=a.z; v[3]=a.w;
                v[4]=b.x; v[5]=b.y; v[6]=b.z; v[7]=b.w;
            } else if (lq == 1) {
                float4 a = *(const float4*)(p + 8);
                v[0]=a.x; v[1]=a.y; v[2]=a.z; v[3]=a.w;
            }
            #pragma unroll
            for (int j = 0; j < 8; ++j) Apos[j] = (short)bfbits(v[j]);
        }
        f32x4 enc_d[4], emb_d[4];
        #pragma unroll
        for (int nt = 0; nt < 4; ++nt) {
            f32x4 c = {benc[nt], benc[nt], benc[nt], benc[nt]};
            enc_d[nt] = __builtin_amdgcn_mfma_f32_16x16x32_bf16(Apos, Wenc[nt], c, 0, 0, 0);
            f32x4 e = {bedge[nt], bedge[nt], bedge[nt], bedge[nt]};
            emb_d[nt] = e;
        }
        // emb MFMA, kt-outer (A transient)
        #pragma unroll
        for (int kt = 0; kt < 8; ++kt) {
            bf16x8 Ae = (kt < 4)
                ? ld8cvt(ht + row * 128 + kt * 32 + lq * 8)
                : ld8cvt(hs + row * 128 + (kt - 4) * 32 + lq * 8);
            #pragma unroll
            for (int nt = 0; nt < 4; ++nt)
                emb_d[nt] = __builtin_amdgcn_mfma_f32_16x16x32_bf16(Ae, Wedge[kt][nt], emb_d[nt], 0, 0, 0);
        }
        // relu + write x tile to LDS (row-major [16][128])
        short* xb = xbuf[w];
        #pragma unroll
        for (int nt = 0; nt < 4; ++nt) {
            #pragma unroll
            for (int r = 0; r < 4; ++r) {
                const int m = lq * 4 + r;
                const int o = nt * 16 + lr;
                xb[m * 128 + o]      = (short)bfbits(fmaxf(enc_d[nt][r], 0.f));
                xb[m * 128 + 64 + o] = (short)bfbits(fmaxf(emb_d[nt][r], 0.f));
            }
        }
        // coalesced copy-out: 4KB -> superslot x region
        const uint4* src = (const uint4*)xb;
        uint4* dst = (uint4*)(obase + F0 * 1024 + 12288);
        #pragma unroll
        for (int i = 0; i < 4; ++i) dst[i * 64 + lane] = src[i * 64 + lane];
    }
}

// ---------------------------------------------------------------------------
// K1b: gi = x@W_ihT + b_ih -> bf16 frag-order in superslot [0,12288).
// 512 blocks x 256 thr, 8 chunks x 4 tiles. Per wave: 24 W_ih B-frags in regs
// covering o-slice {g*128 + w*32 + n2*16}.
// ---------------------------------------------------------------------------
__global__ __launch_bounds__(256, 2) void k_gi(
    const float* __restrict__ W_ih, const float* __restrict__ b_ih,
    char* __restrict__ obase)
{
    const int tid = threadIdx.x;
    const int w = tid >> 6, lane = tid & 63;
    const int lr = lane & 15, lq = lane >> 4;

    bf16x8 Wf[6][4];
    float bih[6];
    #pragma unroll
    for (int g = 0; g < 3; ++g)
        #pragma unroll
        for (int n2 = 0; n2 < 2; ++n2) {
            const int jj = g * 2 + n2;
            const int o = g * 128 + w * 32 + n2 * 16 + lr;
            bih[jj] = b_ih[o];
            #pragma unroll
            for (int kt = 0; kt < 4; ++kt)
                Wf[jj][kt] = ld8cvt(W_ih + (size_t)o * 128 + kt * 32 + lq * 8);
        }

    for (int chunk = 0; chunk < 8; ++chunk) {
        #pragma unroll 1
        for (int tile = 0; tile < 4; ++tile) {
            const size_t F0 = (size_t)blockIdx.x * 512 + chunk * 64 + tile * 16;
            char* ss = obase + F0 * 1024;
            bf16x8 A[4];
            #pragma unroll
            for (int kt = 0; kt < 4; ++kt)
                A[kt] = *(const bf16x8*)(ss + 12288 + lr * 256 + kt * 64 + lq * 16);
            #pragma unroll
            for (int jj = 0; jj < 6; ++jj) {
                f32x4 acc = {bih[jj], bih[jj], bih[jj], bih[jj]};
                #pragma unroll
                for (int kt = 0; kt < 4; ++kt)
                    acc = __builtin_amdgcn_mfma_f32_16x16x32_bf16(A[kt], Wf[jj][kt], acc, 0, 0, 0);
                const int nt = (jj >> 1) * 8 + w * 2 + (jj & 1);
                uint2 u;
                u.x = pack2(acc[0], acc[1]);
                u.y = pack2(acc[2], acc[3]);
                *(uint2*)(ss + nt * 512 + lane * 8) = u;
            }
        }
    }
}

// ---------------------------------------------------------------------------
// K2: GRU scan. 64 blocks (1 env = 16 rows) x 256 thr. W_hh B-frags in regs,
// h ping-pong in swizzled LDS bf16, gi prefetched 1 step ahead.
// ys col-major bf16 -> superslot tail. h_last f32 -> d_out tail.
// ---------------------------------------------------------------------------
__global__ __launch_bounds__(256, 1) void k_scan(
    const float* __restrict__ h0, const float* __restrict__ masks,
    const float* __restrict__ W_hh, const float* __restrict__ b_hh,
    char* __restrict__ obase, float* __restrict__ dout)
{
    const int tid = threadIdx.x;
    const int w = tid >> 6, lane = tid & 63;
    const int lr = lane & 15, lq = lane >> 4;
    const int blk = blockIdx.x;          // env index
    const int r0 = blk * 16;

    __shared__ __align__(16) short hbf[2][2048];   // [16][128] bf16, XOR-swizzled

    bf16x8 Wf[6][4];
    float bhh[6];
    #pragma unroll
    for (int g = 0; g < 3; ++g)
        #pragma unroll
        for (int n2 = 0; n2 < 2; ++n2) {
            const int jj = g * 2 + n2;
            const int o = g * 128 + w * 32 + n2 * 16 + lr;
            bhh[jj] = b_hh[o];
            #pragma unroll
            for (int kt = 0; kt < 4; ++kt)
                Wf[jj][kt] = ld8cvt(W_hh + (size_t)o * 128 + kt * 32 + lq * 8);
        }

    // h_old f32 regs: [n2][r] at (m=lq*4+r, k=w*32+n2*16+lr)
    float hold[2][4];
    #pragma unroll
    for (int n2 = 0; n2 < 2; ++n2)
        #pragma unroll
        for (int r = 0; r < 4; ++r)
            hold[n2][r] = h0[(size_t)(r0 + lq * 4 + r) * 128 + w * 32 + n2 * 16 + lr];

    // init hbf[0] (each thread 8 elems, 16B granule, swizzled)
    {
        const int m = tid >> 4;
        const int kb = (tid & 15) * 16;
        bf16x8 hv = ld8cvt(h0 + (size_t)(r0 + m) * 128 + (tid & 15) * 8);
        *(bf16x8*)((char*)hbf[0] + m * 256 + (kb ^ ((m & 7) << 4))) = hv;
    }

    // prefetch t=0 gi + mask
    uint2 gic[6];
    {
        const char* gp = obase + (size_t)r0 * 1024;
        #pragma unroll
        for (int jj = 0; jj < 6; ++jj) {
            const int nt = (jj >> 1) * 8 + w * 2 + (jj & 1);
            gic[jj] = *(const uint2*)(gp + nt * 512 + lane * 8);
        }
    }
    float mcur = masks[blk];
    __syncthreads();

    for (int t = 0; t < TT; ++t) {
        const int cur = t & 1;
        // A-frags from hbf[cur] (swizzled b128 reads)
        bf16x8 A[4];
        #pragma unroll
        for (int kt = 0; kt < 4; ++kt) {
            const int kb = kt * 64 + lq * 16;
            A[kt] = *(const bf16x8*)((const char*)hbf[cur] + lr * 256 + (kb ^ ((lr & 7) << 4)));
        }
        // prefetch next gi + mask (hides global latency under MFMA/pointwise)
        uint2 gnx[6];
        float mnx = 0.f;
        if (t < TT - 1) {
            const char* gp = obase + (size_t)((t + 1) * 1024 + r0) * 1024;
            #pragma unroll
            for (int jj = 0; jj < 6; ++jj) {
                const int nt = (jj >> 1) * 8 + w * 2 + (jj & 1);
                gnx[jj] = *(const uint2*)(gp + nt * 512 + lane * 8);
            }
            mnx = masks[(t + 1) * 64 + blk];
        } else {
            #pragma unroll
            for (int jj = 0; jj < 6; ++jj) { gnx[jj].x = 0u; gnx[jj].y = 0u; }
        }
        // mask (binary in this workload; general path kept for safety)
        const float mt = mcur;
        if (mt == 0.0f) {
            #pragma unroll
            for (int kt = 0; kt < 4; ++kt) {
                bf16x8 z;
                #pragma unroll
                for (int j = 0; j < 8; ++j) z[j] = 0;
                A[kt] = z;
            }
            #pragma unroll
            for (int n2 = 0; n2 < 2; ++n2)
                #pragma unroll
                for (int r = 0; r < 4; ++r) hold[n2][r] = 0.f;
        } else if (mt != 1.0f) {
            #pragma unroll
            for (int n2 = 0; n2 < 2; ++n2)
                #pragma unroll
                for (int r = 0; r < 4; ++r) hold[n2][r] *= mt;
            #pragma unroll
            for (int kt = 0; kt < 4; ++kt) {
                bf16x8 a = A[kt];
                #pragma unroll
                for (int j = 0; j < 8; ++j)
                    a[j] = (short)bfbits(bf2f((uint16_t)a[j]) * mt);
                A[kt] = a;
            }
        }
        // gh MFMAs
        f32x4 acc[6];
        #pragma unroll
        for (int jj = 0; jj < 6; ++jj) {
            f32x4 c = {bhh[jj], bhh[jj], bhh[jj], bhh[jj]};
            #pragma unroll
            for (int kt = 0; kt < 4; ++kt)
                c = __builtin_amdgcn_mfma_f32_16x16x32_bf16(A[kt], Wf[jj][kt], c, 0, 0, 0);
            acc[jj] = c;
        }
        // pointwise + ys store + next-h LDS write
        char* ssy = obase + (size_t)(t * 1024 + r0) * 1024 + 12288;
        short* hb = hbf[cur ^ 1];
        #pragma unroll
        for (int n2 = 0; n2 < 2; ++n2) {
            float hn[4];
            #pragma unroll
            for (int r = 0; r < 4; ++r) {
                const uint32_t urz = (r < 2) ? gic[n2].x     : gic[n2].y;
                const uint32_t uzz = (r < 2) ? gic[2 + n2].x : gic[2 + n2].y;
                const uint32_t unn = (r < 2) ? gic[4 + n2].x : gic[4 + n2].y;
                const float gr = bf2f((r & 1) ? (urz >> 16) : (urz & 0xffffu));
                const float gz = bf2f((r & 1) ? (uzz >> 16) : (uzz & 0xffffu));
                const float gn = bf2f((r & 1) ? (unn >> 16) : (unn & 0xffffu));
                const float rr = 1.f / (1.f + __expf(-(gr + acc[n2][r])));
                const float zz = 1.f / (1.f + __expf(-(gz + acc[2 + n2][r])));
                const float pre = gn + rr * acc[4 + n2][r];
                const float ex = __expf(2.f * pre);
                const float nn = 1.f - 2.f / (ex + 1.f);    // tanh(pre)
                hn[r] = (1.f - zz) * nn + zz * hold[n2][r];
                hold[n2][r] = hn[r];
            }
            const int k = w * 32 + n2 * 16 + lr;
            uint2 u;
            u.x = pack2(hn[0], hn[1]);
            u.y = pack2(hn[2], hn[3]);
            *(uint2*)(ssy + k * 32 + lq * 8) = u;           // ys col-major
            #pragma unroll
            for (int r = 0; r < 4; ++r) {
                const int m = lq * 4 + r;
                const int kb = k * 2;
                *(short*)((char*)hb + m * 256 + (kb ^ ((m & 7) << 4))) = (short)bfbits(hn[r]);
            }
        }
        #pragma unroll
        for (int jj = 0; jj < 6; ++jj) gic[jj] = gnx[jj];
        mcur = mnx;
        __syncthreads();
    }
    // h_last f32
    #pragma unroll
    for (int n2 = 0; n2 < 2; ++n2)
        #pragma unroll
        for (int r = 0; r < 4; ++r)
            dout[OUT_ELEMS + (size_t)(r0 + lq * 4 + r) * 128 + w * 32 + n2 * 16 + lr] = hold[n2][r];
}

// ---------------------------------------------------------------------------
// K3: out = ys@W_outT + b_out (f32, overwrites superslot). 512 blocks x 8 its
// x 4 superslots. Per wave: 16 W_out B-frags in regs (o-slice w*64..w*64+63).
// ys staged via LDS (col-major -> conflict-free scalar gathers).
// ---------------------------------------------------------------------------
__global__ __launch_bounds__(256, 2) void k_out(
    const float* __restrict__ W_out, const float* __restrict__ b_out,
    char* __restrict__ obase)
{
    const int tid = threadIdx.x;
    const int w = tid >> 6, lane = tid & 63;
    const int lr = lane & 15, lq = lane >> 4;

    __shared__ __align__(16) uint4 ysbuf[4][256];  // 4 x 4KB

    bf16x8 Wf[4][4];
    float bo[4];
    #pragma unroll
    for (int ntl = 0; ntl < 4; ++ntl) {
        const int o = w * 64 + ntl * 16 + lr;
        bo[ntl] = b_out[o];
        #pragma unroll
        for (int kt = 0; kt < 4; ++kt)
            Wf[ntl][kt] = ld8cvt(W_out + (size_t)o * 128 + kt * 32 + lq * 8);
    }

    for (int it = 0; it < 8; ++it) {
        const int S0 = blockIdx.x * 32 + it * 4;
        {
            const int tb = tid >> 6, li = tid & 63;
            const uint4* src = (const uint4*)(obase + (size_t)(S0 + tb) * 16384 + 12288);
            #pragma unroll
            for (int i = 0; i < 4; ++i) ysbuf[tb][li + i * 64] = src[li + i * 64];
        }
        __syncthreads();
        #pragma unroll 1
        for (int tile = 0; tile < 4; ++tile) {
            const short* yb = (const short*)ysbuf[tile];
            bf16x8 A[4];
            #pragma unroll
            for (int kt = 0; kt < 4; ++kt) {
                bf16x8 a;
                #pragma unroll
                for (int j = 0; j < 8; ++j) {
                    const int k = kt * 32 + lq * 8 + j;
                    a[j] = yb[k * 16 + lr];     // col-major gather, conflict-free
                }
                A[kt] = a;
            }
            char* ssp = obase + (size_t)(S0 + tile) * 16384;
            #pragma unroll
            for (int ntl = 0; ntl < 4; ++ntl) {
                f32x4 acc = {bo[ntl], bo[ntl], bo[ntl], bo[ntl]};
                #pragma unroll
                for (int kt = 0; kt < 4; ++kt)
                    acc = __builtin_amdgcn_mfma_f32_16x16x32_bf16(A[kt], Wf[ntl][kt], acc, 0, 0, 0);
                const int o = w * 64 + ntl * 16 + lr;
                #pragma unroll
                for (int r = 0; r < 4; ++r) {
                    const int m = lq * 4 + r;
                    *(float*)(ssp + m * 1024 + o * 4) = acc[r];
                }
            }
        }
        __syncthreads();
    }
}

extern "C" void kernel_launch(void* const* d_in, const int* in_sizes, int n_in,
                              void* d_out, int out_size, void* d_ws, size_t ws_size,
                              hipStream_t stream) {
    const float* pos    = (const float*)d_in[0];
    const float* ht     = (const float*)d_in[1];
    const float* hs     = (const float*)d_in[2];
    const float* h0     = (const float*)d_in[3];
    const float* masks  = (const float*)d_in[4];
    const float* W_enc  = (const float*)d_in[5];
    const float* b_enc  = (const float*)d_in[6];
    const float* W_edge = (const float*)d_in[7];
    const float* b_edge = (const float*)d_in[8];
    const float* W_ih   = (const float*)d_in[9];
    const float* b_ih   = (const float*)d_in[10];
    const float* W_hh   = (const float*)d_in[11];
    const float* b_hh   = (const float*)d_in[12];
    const float* W_out  = (const float*)d_in[13];
    const float* b_out  = (const float*)d_in[14];
    char*  obase = (char*)d_out;
    float* out   = (float*)d_out;

    hipLaunchKernelGGL(k_embed, dim3(512), dim3(256), 0, stream,
                       pos, ht, hs, W_enc, b_enc, W_edge, b_edge, obase);
    hipLaunchKernelGGL(k_gi, dim3(512), dim3(256), 0, stream,
                       W_ih, b_ih, obase);
    hipLaunchKernelGGL(k_scan, dim3(64), dim3(256), 0, stream,
                       h0, masks, W_hh, b_hh, obase, out);
    hipLaunchKernelGGL(k_out, dim3(512), dim3(256), 0, stream,
                       W_out, b_out, obase);
}

// Round 6
// 919.475 us; speedup vs baseline: 19.9190x; 1.0965x over previous
//
#include <hip/hip_runtime.h>
#include <hip/hip_bf16.h>
#include <stdint.h>

#define TT 256
#define ROWSG 1024
#define OUT_ELEMS ((size_t)TT * ROWSG * 256)   // 67,108,864 f32

// Superslot layout per (t, rtile16): 16 consecutive 1KB out-row slots = 16KB:
//   [0,12288):     gi frags, 24 nt x 64 lanes x 8B bf16     [k_gi -> k_scan]
//   [12288,16384): x bf16 row-major [16][128]               [k_embed -> k_gi]
//                  then ys bf16 col-major [128][16]         [k_scan -> k_out]
//   k_out overwrites the whole superslot with out f32 [16][256].

typedef __attribute__((ext_vector_type(8))) short bf16x8;
typedef __attribute__((ext_vector_type(4))) float f32x4;

__device__ __forceinline__ uint32_t pk2(float a, float b) {
    union { __hip_bfloat162 h; uint32_t u; } cv;
    cv.h = __float22bfloat162_rn(float2{a, b});
    return cv.u;
}
__device__ __forceinline__ uint16_t bf1(float a) {
    union { __hip_bfloat16 h; uint16_t u; } cv;
    cv.h = __float2bfloat16(a);
    return cv.u;
}
__device__ __forceinline__ float bf2f(uint32_t b16) {
    return __uint_as_float(b16 << 16);
}
// 8 consecutive f32 (16B aligned) -> bf16x8 via cvt_pk
__device__ __forceinline__ bf16x8 ld8cvt(const float* p) {
    float4 f0 = *(const float4*)p;
    float4 f1 = *(const float4*)(p + 4);
    union { bf16x8 v; uint32_t u[4]; } r;
    r.u[0] = pk2(f0.x, f0.y);
    r.u[1] = pk2(f0.z, f0.w);
    r.u[2] = pk2(f1.x, f1.y);
    r.u[3] = pk2(f1.z, f1.w);
    return r.v;
}

// ---------------------------------------------------------------------------
// K1a: enc = relu(pos@W_encT+b), emb = relu([ht|hs]@W_edgeT+b) -> x bf16.
// ---------------------------------------------------------------------------
__global__ __launch_bounds__(256, 2) void k_embed(
    const float* __restrict__ pos, const float* __restrict__ ht,
    const float* __restrict__ hs,
    const float* __restrict__ W_enc, const float* __restrict__ b_enc,
    const float* __restrict__ W_edge, const float* __restrict__ b_edge,
    char* __restrict__ obase)
{
    const int tid = threadIdx.x;
    const int w = tid >> 6, lane = tid & 63;
    const int lr = lane & 15, lq = lane >> 4;

    __shared__ __align__(16) short xbuf[4][2048];  // per-wave 16x128 bf16

    // --- W_enc B-frags (K=12 zero-padded to 32), 4 n-tiles ---
    bf16x8 Wenc[4];
    float benc[4];
    #pragma unroll
    for (int nt = 0; nt < 4; ++nt) {
        const int o = nt * 16 + lr;
        benc[nt] = b_enc[o];
        float v[8];
        #pragma unroll
        for (int j = 0; j < 8; ++j) v[j] = 0.f;
        const float* p = W_enc + o * 12;
        if (lq == 0) {
            float4 a = *(const float4*)p;
            float4 b = *(const float4*)(p + 4);
            v[0]=a.x; v[1]=a.y; v[2]=a.z; v[3]=a.w;
            v[4]=b.x; v[5]=b.y; v[6]=b.z; v[7]=b.w;
        } else if (lq == 1) {
            float4 a = *(const float4*)(p + 8);
            v[0]=a.x; v[1]=a.y; v[2]=a.z; v[3]=a.w;
        }
        union { bf16x8 vv; uint32_t u[4]; } f;
        f.u[0] = pk2(v[0], v[1]); f.u[1] = pk2(v[2], v[3]);
        f.u[2] = pk2(v[4], v[5]); f.u[3] = pk2(v[6], v[7]);
        Wenc[nt] = f.vv;
    }
    // --- W_edge B-frags: [kt 0..7][nt 0..3] ---
    bf16x8 Wedge[8][4];
    float bedge[4];
    #pragma unroll
    for (int nt = 0; nt < 4; ++nt) {
        const int o = nt * 16 + lr;
        bedge[nt] = b_edge[o];
        #pragma unroll
        for (int kt = 0; kt < 8; ++kt)
            Wedge[kt][nt] = ld8cvt(W_edge + (size_t)o * 256 + kt * 32 + lq * 8);
    }

    for (int chunk = 0; chunk < 8; ++chunk) {
        const size_t F0 = (size_t)blockIdx.x * 512 + chunk * 64 + w * 16;
        const size_t row = F0 + lr;

        bf16x8 Apos;
        {
            float v[8];
            #pragma unroll
            for (int j = 0; j < 8; ++j) v[j] = 0.f;
            const float* p = pos + row * 12;
            if (lq == 0) {
                float4 a = *(const float4*)p;
                float4 b = *(const float4*)(p + 4);
                v[0]=a.x; v[1]=a.y; v[2]=a.z; v[3]=a.w;
                v[4]=b.x; v[5]=b.y; v[6]=b.z; v[7]=b.w;
            } else if (lq == 1) {
                float4 a = *(const float4*)(p + 8);
                v[0]=a.x; v[1]=a.y; v[2]=a.z; v[3]=a.w;
            }
            union { bf16x8 vv; uint32_t u[4]; } f;
            f.u[0] = pk2(v[0], v[1]); f.u[1] = pk2(v[2], v[3]);
            f.u[2] = pk2(v[4], v[5]); f.u[3] = pk2(v[6], v[7]);
            Apos = f.vv;
        }
        f32x4 enc_d[4], emb_d[4];
        #pragma unroll
        for (int nt = 0; nt < 4; ++nt) {
            f32x4 c = {benc[nt], benc[nt], benc[nt], benc[nt]};
            enc_d[nt] = __builtin_amdgcn_mfma_f32_16x16x32_bf16(Apos, Wenc[nt], c, 0, 0, 0);
            f32x4 e = {bedge[nt], bedge[nt], bedge[nt], bedge[nt]};
            emb_d[nt] = e;
        }
        #pragma unroll
        for (int kt = 0; kt < 8; ++kt) {
            bf16x8 Ae = (kt < 4)
                ? ld8cvt(ht + row * 128 + kt * 32 + lq * 8)
                : ld8cvt(hs + row * 128 + (kt - 4) * 32 + lq * 8);
            #pragma unroll
            for (int nt = 0; nt < 4; ++nt)
                emb_d[nt] = __builtin_amdgcn_mfma_f32_16x16x32_bf16(Ae, Wedge[kt][nt], emb_d[nt], 0, 0, 0);
        }
        short* xb = xbuf[w];
        #pragma unroll
        for (int nt = 0; nt < 4; ++nt) {
            #pragma unroll
            for (int r = 0; r < 4; ++r) {
                const int m = lq * 4 + r;
                const int o = nt * 16 + lr;
                xb[m * 128 + o]      = (short)bf1(fmaxf(enc_d[nt][r], 0.f));
                xb[m * 128 + 64 + o] = (short)bf1(fmaxf(emb_d[nt][r], 0.f));
            }
        }
        const uint4* src = (const uint4*)xb;
        uint4* dst = (uint4*)(obase + F0 * 1024 + 12288);
        #pragma unroll
        for (int i = 0; i < 4; ++i) dst[i * 64 + lane] = src[i * 64 + lane];
    }
}

// ---------------------------------------------------------------------------
// K1b: gi = x@W_ihT + b_ih -> bf16 frag-order in superslot [0,12288).
// x staged via swizzled LDS with coalesced loads.
// ---------------------------------------------------------------------------
__global__ __launch_bounds__(256, 2) void k_gi(
    const float* __restrict__ W_ih, const float* __restrict__ b_ih,
    char* __restrict__ obase)
{
    const int tid = threadIdx.x;
    const int w = tid >> 6, lane = tid & 63;
    const int lr = lane & 15, lq = lane >> 4;

    __shared__ __align__(16) char xl[16384];   // 4 tiles x [16][128] bf16, swizzled

    bf16x8 Wf[6][4];
    float bih[6];
    #pragma unroll
    for (int g = 0; g < 3; ++g)
        #pragma unroll
        for (int n2 = 0; n2 < 2; ++n2) {
            const int jj = g * 2 + n2;
            const int o = g * 128 + w * 32 + n2 * 16 + lr;
            bih[jj] = b_ih[o];
            #pragma unroll
            for (int kt = 0; kt < 4; ++kt)
                Wf[jj][kt] = ld8cvt(W_ih + (size_t)o * 128 + kt * 32 + lq * 8);
        }

    // precomputed swizzled addresses
    const int stg_m = tid >> 4, stg_kb = tid & 15;
    const int stg_off = stg_m * 256 + ((stg_kb * 16) ^ (stg_m << 4));
    int axoff[4];
    #pragma unroll
    for (int kt = 0; kt < 4; ++kt)
        axoff[kt] = lr * 256 + ((kt * 64 + lq * 16) ^ (lr << 4));

    for (int chunk = 0; chunk < 8; ++chunk) {
        const size_t F0c = (size_t)blockIdx.x * 512 + chunk * 64;
        // stage 4 tiles' x (16KB), coalesced 4KB per iteration
        #pragma unroll
        for (int i = 0; i < 4; ++i) {
            const uint4 val = *(const uint4*)(obase + (F0c + i * 16) * 1024 + 12288 + tid * 16);
            *(uint4*)(xl + i * 4096 + stg_off) = val;
        }
        __syncthreads();
        #pragma unroll 1
        for (int tile = 0; tile < 4; ++tile) {
            bf16x8 A[4];
            #pragma unroll
            for (int kt = 0; kt < 4; ++kt)
                A[kt] = *(const bf16x8*)(xl + tile * 4096 + axoff[kt]);
            char* ss = obase + (F0c + tile * 16) * 1024;
            #pragma unroll
            for (int jj = 0; jj < 6; ++jj) {
                f32x4 acc = {bih[jj], bih[jj], bih[jj], bih[jj]};
                #pragma unroll
                for (int kt = 0; kt < 4; ++kt)
                    acc = __builtin_amdgcn_mfma_f32_16x16x32_bf16(A[kt], Wf[jj][kt], acc, 0, 0, 0);
                const int nt = (jj >> 1) * 8 + w * 2 + (jj & 1);
                uint2 u;
                u.x = pk2(acc[0], acc[1]);
                u.y = pk2(acc[2], acc[3]);
                *(uint2*)(ss + nt * 512 + lane * 8) = u;
            }
        }
        __syncthreads();
    }
}

// ---------------------------------------------------------------------------
// K2: GRU scan. 64 blocks (1 env = 16 rows) x 256 thr. Mask pre-folded at
// h-write time (no branchy A masking); cvt_pk packing; precomputed swizzled
// LDS offsets; 2-step unroll for static ping-pong index.
// ---------------------------------------------------------------------------
__global__ __launch_bounds__(256, 1) void k_scan(
    const float* __restrict__ h0, const float* __restrict__ masks,
    const float* __restrict__ W_hh, const float* __restrict__ b_hh,
    char* __restrict__ obase, float* __restrict__ dout)
{
    const int tid = threadIdx.x;
    const int w = tid >> 6, lane = tid & 63;
    const int lr = lane & 15, lq = lane >> 4;
    const int blk = blockIdx.x;          // env index
    const int r0 = blk * 16;

    __shared__ __align__(16) char hbf[2 * 4096];   // [16][128] bf16 x2, swizzled
    __shared__ float msk[TT];

    msk[tid] = masks[tid * 64 + blk];    // 256 threads = 256 t values

    bf16x8 Wf[6][4];
    float bhh[6];
    #pragma unroll
    for (int g = 0; g < 3; ++g)
        #pragma unroll
        for (int n2 = 0; n2 < 2; ++n2) {
            const int jj = g * 2 + n2;
            const int o = g * 128 + w * 32 + n2 * 16 + lr;
            bhh[jj] = b_hh[o];
            #pragma unroll
            for (int kt = 0; kt < 4; ++kt)
                Wf[jj][kt] = ld8cvt(W_hh + (size_t)o * 128 + kt * 32 + lq * 8);
        }

    // precomputed swizzled offsets
    int roff[4], woff[2][4], gioff[6], ysoff[2];
    #pragma unroll
    for (int kt = 0; kt < 4; ++kt)
        roff[kt] = lr * 256 + ((kt * 64 + lq * 16) ^ (lr << 4));
    #pragma unroll
    for (int n2 = 0; n2 < 2; ++n2) {
        ysoff[n2] = (w * 32 + n2 * 16 + lr) * 32 + lq * 8;
        #pragma unroll
        for (int r = 0; r < 4; ++r) {
            const int m = lq * 4 + r;
            const int k = w * 32 + n2 * 16 + lr;
            woff[n2][r] = m * 256 + ((k * 2) ^ (m << 4));
        }
    }
    #pragma unroll
    for (int jj = 0; jj < 6; ++jj) {
        const int nt = (jj >> 1) * 8 + w * 2 + (jj & 1);
        gioff[jj] = nt * 512 + lane * 8;
    }

    __syncthreads();                     // msk ready
    const float m0 = msk[0];

    // hold = h0 * m0 (masked state for step 0)
    float hold[2][4];
    #pragma unroll
    for (int n2 = 0; n2 < 2; ++n2)
        #pragma unroll
        for (int r = 0; r < 4; ++r)
            hold[n2][r] = h0[(size_t)(r0 + lq * 4 + r) * 128 + w * 32 + n2 * 16 + lr] * m0;

    // hbf[0] = bf16(h0 * m0)
    {
        const int m = tid >> 4, kb = tid & 15;
        const float* hp = h0 + (size_t)(r0 + m) * 128 + kb * 8;
        float4 f0 = *(const float4*)hp;
        float4 f1 = *(const float4*)(hp + 4);
        union { bf16x8 v; uint32_t u[4]; } hv;
        hv.u[0] = pk2(f0.x * m0, f0.y * m0);
        hv.u[1] = pk2(f0.z * m0, f0.w * m0);
        hv.u[2] = pk2(f1.x * m0, f1.y * m0);
        hv.u[3] = pk2(f1.z * m0, f1.w * m0);
        *(bf16x8*)(hbf + m * 256 + ((kb * 16) ^ (m << 4))) = hv.v;
    }

    // prefetch t=0 gi
    uint2 gic[6];
    {
        const char* gp = obase + (size_t)r0 * 1024;
        #pragma unroll
        for (int jj = 0; jj < 6; ++jj)
            gic[jj] = *(const uint2*)(gp + gioff[jj]);
    }
    const char* gnext = obase + (1 << 20) + (size_t)r0 * 1024;
    char* ysp = obase + (size_t)r0 * 1024 + 12288;
    char* const hbase = hbf;
    __syncthreads();                     // hbf[0] ready

#define STEP(B, T) { \
    bf16x8 A[4]; \
    _Pragma("unroll") for (int kt = 0; kt < 4; ++kt) \
        A[kt] = *(const bf16x8*)(hbase + (B) * 4096 + roff[kt]); \
    uint2 gnx[6]; float mnx; \
    if ((T) < TT - 1) { \
        _Pragma("unroll") for (int jj = 0; jj < 6; ++jj) \
            gnx[jj] = *(const uint2*)(gnext + gioff[jj]); \
        mnx = msk[(T) + 1]; \
    } else { \
        _Pragma("unroll") for (int jj = 0; jj < 6; ++jj) { gnx[jj].x = 0u; gnx[jj].y = 0u; } \
        mnx = 1.0f; \
    } \
    f32x4 acc[6]; \
    _Pragma("unroll") for (int jj = 0; jj < 6; ++jj) { \
        f32x4 c = {bhh[jj], bhh[jj], bhh[jj], bhh[jj]}; \
        _Pragma("unroll") for (int kt = 0; kt < 4; ++kt) \
            c = __builtin_amdgcn_mfma_f32_16x16x32_bf16(A[kt], Wf[jj][kt], c, 0, 0, 0); \
        acc[jj] = c; \
    } \
    _Pragma("unroll") for (int n2 = 0; n2 < 2; ++n2) { \
        float hn[4]; \
        _Pragma("unroll") for (int r = 0; r < 4; ++r) { \
            const uint32_t urz = (r < 2) ? gic[n2].x : gic[n2].y; \
            const uint32_t uzz = (r < 2) ? gic[2 + n2].x : gic[2 + n2].y; \
            const uint32_t unn = (r < 2) ? gic[4 + n2].x : gic[4 + n2].y; \
            const float gr = bf2f((r & 1) ? (urz >> 16) : (urz & 0xffffu)); \
            const float gz = bf2f((r & 1) ? (uzz >> 16) : (uzz & 0xffffu)); \
            const float gn = bf2f((r & 1) ? (unn >> 16) : (unn & 0xffffu)); \
            const float rr = 1.f / (1.f + __expf(-(gr + acc[n2][r]))); \
            const float zz = 1.f / (1.f + __expf(-(gz + acc[2 + n2][r]))); \
            const float pre = gn + rr * acc[4 + n2][r]; \
            const float ex = __expf(2.f * pre); \
            const float nn = 1.f - 2.f / (ex + 1.f); \
            hn[r] = nn + zz * (hold[n2][r] - nn); \
        } \
        uint2 u; u.x = pk2(hn[0], hn[1]); u.y = pk2(hn[2], hn[3]); \
        *(uint2*)(ysp + ysoff[n2]) = u; \
        _Pragma("unroll") for (int r = 0; r < 4; ++r) { \
            const float hx = hn[r] * mnx; \
            hold[n2][r] = hx; \
            *(uint16_t*)(hbase + ((B) ^ 1) * 4096 + woff[n2][r]) = bf1(hx); \
        } \
    } \
    _Pragma("unroll") for (int jj = 0; jj < 6; ++jj) gic[jj] = gnx[jj]; \
    gnext += (1 << 20); ysp += (1 << 20); \
    __syncthreads(); \
}

    for (int t2 = 0; t2 < TT; t2 += 2) {
        STEP(0, t2)
        STEP(1, t2 + 1)
    }
#undef STEP

    // h_last f32 (hold holds unmasked h_255 since mnx=1 at t=255)
    #pragma unroll
    for (int n2 = 0; n2 < 2; ++n2)
        #pragma unroll
        for (int r = 0; r < 4; ++r)
            dout[OUT_ELEMS + (size_t)(r0 + lq * 4 + r) * 128 + w * 32 + n2 * 16 + lr] = hold[n2][r];
}

// ---------------------------------------------------------------------------
// K3: out = ys@W_outT + b_out (f32, overwrites superslot).
// ---------------------------------------------------------------------------
__global__ __launch_bounds__(256, 2) void k_out(
    const float* __restrict__ W_out, const float* __restrict__ b_out,
    char* __restrict__ obase)
{
    const int tid = threadIdx.x;
    const int w = tid >> 6, lane = tid & 63;
    const int lr = lane & 15, lq = lane >> 4;

    __shared__ __align__(16) uint4 ysbuf[4][256];  // 4 x 4KB

    bf16x8 Wf[4][4];
    float bo[4];
    #pragma unroll
    for (int ntl = 0; ntl < 4; ++ntl) {
        const int o = w * 64 + ntl * 16 + lr;
        bo[ntl] = b_out[o];
        #pragma unroll
        for (int kt = 0; kt < 4; ++kt)
            Wf[ntl][kt] = ld8cvt(W_out + (size_t)o * 128 + kt * 32 + lq * 8);
    }

    for (int it = 0; it < 8; ++it) {
        const int S0 = blockIdx.x * 32 + it * 4;
        {
            const int tb = tid >> 6, li = tid & 63;
            const uint4* src = (const uint4*)(obase + (size_t)(S0 + tb) * 16384 + 12288);
            #pragma unroll
            for (int i = 0; i < 4; ++i) ysbuf[tb][li + i * 64] = src[li + i * 64];
        }
        __syncthreads();
        #pragma unroll 1
        for (int tile = 0; tile < 4; ++tile) {
            const short* yb = (const short*)ysbuf[tile];
            bf16x8 A[4];
            #pragma unroll
            for (int kt = 0; kt < 4; ++kt) {
                bf16x8 a;
                #pragma unroll
                for (int j = 0; j < 8; ++j) {
                    const int k = kt * 32 + lq * 8 + j;
                    a[j] = yb[k * 16 + lr];     // col-major gather, conflict-free
                }
                A[kt] = a;
            }
            char* ssp = obase + (size_t)(S0 + tile) * 16384;
            #pragma unroll
            for (int ntl = 0; ntl < 4; ++ntl) {
                f32x4 acc = {bo[ntl], bo[ntl], bo[ntl], bo[ntl]};
                #pragma unroll
                for (int kt = 0; kt < 4; ++kt)
                    acc = __builtin_amdgcn_mfma_f32_16x16x32_bf16(A[kt], Wf[ntl][kt], acc, 0, 0, 0);
                const int o = w * 64 + ntl * 16 + lr;
                #pragma unroll
                for (int r = 0; r < 4; ++r) {
                    const int m = lq * 4 + r;
                    *(float*)(ssp + m * 1024 + o * 4) = acc[r];
                }
            }
        }
        __syncthreads();
    }
}

extern "C" void kernel_launch(void* const* d_in, const int* in_sizes, int n_in,
                              void* d_out, int out_size, void* d_ws, size_t ws_size,
                              hipStream_t stream) {
    const float* pos    = (const float*)d_in[0];
    const float* ht     = (const float*)d_in[1];
    const float* hs     = (const float*)d_in[2];
    const float* h0     = (const float*)d_in[3];
    const float* masks  = (const float*)d_in[4];
    const float* W_enc  = (const float*)d_in[5];
    const float* b_enc  = (const float*)d_in[6];
    const float* W_edge = (const float*)d_in[7];
    const float* b_edge = (const float*)d_in[8];
    const float* W_ih   = (const float*)d_in[9];
    const float* b_ih   = (const float*)d_in[10];
    const float* W_hh   = (const float*)d_in[11];
    const float* b_hh   = (const float*)d_in[12];
    const float* W_out  = (const float*)d_in[13];
    const float* b_out  = (const float*)d_in[14];
    char*  obase = (char*)d_out;
    float* out   = (float*)d_out;

    hipLaunchKernelGGL(k_embed, dim3(512), dim3(256), 0, stream,
                       pos, ht, hs, W_enc, b_enc, W_edge, b_edge, obase);
    hipLaunchKernelGGL(k_gi, dim3(512), dim3(256), 0, stream,
                       W_ih, b_ih, obase);
    hipLaunchKernelGGL(k_scan, dim3(64), dim3(256), 0, stream,
                       h0, masks, W_hh, b_hh, obase, out);
    hipLaunchKernelGGL(k_out, dim3(512), dim3(256), 0, stream,
                       W_out, b_out, obase);
}

// Round 7
// 779.854 us; speedup vs baseline: 23.4852x; 1.1790x over previous
//
#include <hip/hip_runtime.h>
#include <hip/hip_bf16.h>
#include <stdint.h>

#define TT 256
#define ROWSG 1024
#define OUT_ELEMS ((size_t)TT * ROWSG * 256)   // 67,108,864 f32

// Superslot layout per (t, rtile16): 16 consecutive 1KB out-row slots = 16KB:
//   [0,12288):     gi frags, 24 nt x 64 lanes x 8B bf16     [k_gi -> k_scan]
//   [12288,16384): x bf16 row-major [16][128]               [k_embed -> k_gi]
//                  then ys bf16 col-major [128][16]         [k_scan -> k_out]
//   k_out overwrites the whole superslot with out f32 [16][256].

typedef __attribute__((ext_vector_type(8))) short bf16x8;
typedef __attribute__((ext_vector_type(4))) float f32x4;

__device__ __forceinline__ uint32_t pk2(float a, float b) {
    union { __hip_bfloat162 h; uint32_t u; } cv;
    cv.h = __float22bfloat162_rn(float2{a, b});
    return cv.u;
}
__device__ __forceinline__ uint16_t bf1(float a) {
    union { __hip_bfloat16 h; uint16_t u; } cv;
    cv.h = __float2bfloat16(a);
    return cv.u;
}
__device__ __forceinline__ float bf2f(uint32_t b16) {
    return __uint_as_float(b16 << 16);
}
__device__ __forceinline__ float rcpf(float x) {
    return __builtin_amdgcn_rcpf(x);
}
// 8 consecutive f32 (16B aligned) -> bf16x8 via cvt_pk
__device__ __forceinline__ bf16x8 ld8cvt(const float* p) {
    float4 f0 = *(const float4*)p;
    float4 f1 = *(const float4*)(p + 4);
    union { bf16x8 v; uint32_t u[4]; } r;
    r.u[0] = pk2(f0.x, f0.y);
    r.u[1] = pk2(f0.z, f0.w);
    r.u[2] = pk2(f1.x, f1.y);
    r.u[3] = pk2(f1.z, f1.w);
    return r.v;
}

// ---------------------------------------------------------------------------
// K1a: enc = relu(pos@W_encT+b), emb = relu([ht|hs]@W_edgeT+b) -> x bf16.
// ---------------------------------------------------------------------------
__global__ __launch_bounds__(256, 2) void k_embed(
    const float* __restrict__ pos, const float* __restrict__ ht,
    const float* __restrict__ hs,
    const float* __restrict__ W_enc, const float* __restrict__ b_enc,
    const float* __restrict__ W_edge, const float* __restrict__ b_edge,
    char* __restrict__ obase)
{
    const int tid = threadIdx.x;
    const int w = tid >> 6, lane = tid & 63;
    const int lr = lane & 15, lq = lane >> 4;

    __shared__ __align__(16) short xbuf[4][2048];  // per-wave 16x128 bf16

    // --- W_enc B-frags (K=12 zero-padded to 32), 4 n-tiles ---
    bf16x8 Wenc[4];
    float benc[4];
    #pragma unroll
    for (int nt = 0; nt < 4; ++nt) {
        const int o = nt * 16 + lr;
        benc[nt] = b_enc[o];
        float v[8];
        #pragma unroll
        for (int j = 0; j < 8; ++j) v[j] = 0.f;
        const float* p = W_enc + o * 12;
        if (lq == 0) {
            float4 a = *(const float4*)p;
            float4 b = *(const float4*)(p + 4);
            v[0]=a.x; v[1]=a.y; v[2]=a.z; v[3]=a.w;
            v[4]=b.x; v[5]=b.y; v[6]=b.z; v[7]=b.w;
        } else if (lq == 1) {
            float4 a = *(const float4*)(p + 8);
            v[0]=a.x; v[1]=a.y; v[2]=a.z; v[3]=a.w;
        }
        union { bf16x8 vv; uint32_t u[4]; } f;
        f.u[0] = pk2(v[0], v[1]); f.u[1] = pk2(v[2], v[3]);
        f.u[2] = pk2(v[4], v[5]); f.u[3] = pk2(v[6], v[7]);
        Wenc[nt] = f.vv;
    }
    // --- W_edge B-frags: [kt 0..7][nt 0..3] ---
    bf16x8 Wedge[8][4];
    float bedge[4];
    #pragma unroll
    for (int nt = 0; nt < 4; ++nt) {
        const int o = nt * 16 + lr;
        bedge[nt] = b_edge[o];
        #pragma unroll
        for (int kt = 0; kt < 8; ++kt)
            Wedge[kt][nt] = ld8cvt(W_edge + (size_t)o * 256 + kt * 32 + lq * 8);
    }

    for (int chunk = 0; chunk < 8; ++chunk) {
        const size_t F0 = (size_t)blockIdx.x * 512 + chunk * 64 + w * 16;
        const size_t row = F0 + lr;

        bf16x8 Apos;
        {
            float v[8];
            #pragma unroll
            for (int j = 0; j < 8; ++j) v[j] = 0.f;
            const float* p = pos + row * 12;
            if (lq == 0) {
                float4 a = *(const float4*)p;
                float4 b = *(const float4*)(p + 4);
                v[0]=a.x; v[1]=a.y; v[2]=a.z; v[3]=a.w;
                v[4]=b.x; v[5]=b.y; v[6]=b.z; v[7]=b.w;
            } else if (lq == 1) {
                float4 a = *(const float4*)(p + 8);
                v[0]=a.x; v[1]=a.y; v[2]=a.z; v[3]=a.w;
            }
            union { bf16x8 vv; uint32_t u[4]; } f;
            f.u[0] = pk2(v[0], v[1]); f.u[1] = pk2(v[2], v[3]);
            f.u[2] = pk2(v[4], v[5]); f.u[3] = pk2(v[6], v[7]);
            Apos = f.vv;
        }
        f32x4 enc_d[4], emb_d[4];
        #pragma unroll
        for (int nt = 0; nt < 4; ++nt) {
            f32x4 c = {benc[nt], benc[nt], benc[nt], benc[nt]};
            enc_d[nt] = __builtin_amdgcn_mfma_f32_16x16x32_bf16(Apos, Wenc[nt], c, 0, 0, 0);
            f32x4 e = {bedge[nt], bedge[nt], bedge[nt], bedge[nt]};
            emb_d[nt] = e;
        }
        #pragma unroll
        for (int kt = 0; kt < 8; ++kt) {
            bf16x8 Ae = (kt < 4)
                ? ld8cvt(ht + row * 128 + kt * 32 + lq * 8)
                : ld8cvt(hs + row * 128 + (kt - 4) * 32 + lq * 8);
            #pragma unroll
            for (int nt = 0; nt < 4; ++nt)
                emb_d[nt] = __builtin_amdgcn_mfma_f32_16x16x32_bf16(Ae, Wedge[kt][nt], emb_d[nt], 0, 0, 0);
        }
        short* xb = xbuf[w];
        #pragma unroll
        for (int nt = 0; nt < 4; ++nt) {
            #pragma unroll
            for (int r = 0; r < 4; ++r) {
                const int m = lq * 4 + r;
                const int o = nt * 16 + lr;
                xb[m * 128 + o]      = (short)bf1(fmaxf(enc_d[nt][r], 0.f));
                xb[m * 128 + 64 + o] = (short)bf1(fmaxf(emb_d[nt][r], 0.f));
            }
        }
        const uint4* src = (const uint4*)xb;
        uint4* dst = (uint4*)(obase + F0 * 1024 + 12288);
        #pragma unroll
        for (int i = 0; i < 4; ++i) dst[i * 64 + lane] = src[i * 64 + lane];
    }
}

// ---------------------------------------------------------------------------
// K1b: gi = x@W_ihT + b_ih -> bf16 frag-order in superslot [0,12288).
// ---------------------------------------------------------------------------
__global__ __launch_bounds__(256, 2) void k_gi(
    const float* __restrict__ W_ih, const float* __restrict__ b_ih,
    char* __restrict__ obase)
{
    const int tid = threadIdx.x;
    const int w = tid >> 6, lane = tid & 63;
    const int lr = lane & 15, lq = lane >> 4;

    __shared__ __align__(16) char xl[16384];   // 4 tiles x [16][128] bf16, swizzled

    bf16x8 Wf[6][4];
    float bih[6];
    #pragma unroll
    for (int g = 0; g < 3; ++g)
        #pragma unroll
        for (int n2 = 0; n2 < 2; ++n2) {
            const int jj = g * 2 + n2;
            const int o = g * 128 + w * 32 + n2 * 16 + lr;
            bih[jj] = b_ih[o];
            #pragma unroll
            for (int kt = 0; kt < 4; ++kt)
                Wf[jj][kt] = ld8cvt(W_ih + (size_t)o * 128 + kt * 32 + lq * 8);
        }

    const int stg_m = tid >> 4, stg_kb = tid & 15;
    const int stg_off = stg_m * 256 + ((stg_kb * 16) ^ (stg_m << 4));
    int axoff[4];
    #pragma unroll
    for (int kt = 0; kt < 4; ++kt)
        axoff[kt] = lr * 256 + ((kt * 64 + lq * 16) ^ (lr << 4));

    for (int chunk = 0; chunk < 8; ++chunk) {
        const size_t F0c = (size_t)blockIdx.x * 512 + chunk * 64;
        #pragma unroll
        for (int i = 0; i < 4; ++i) {
            const uint4 val = *(const uint4*)(obase + (F0c + i * 16) * 1024 + 12288 + tid * 16);
            *(uint4*)(xl + i * 4096 + stg_off) = val;
        }
        __syncthreads();
        #pragma unroll 1
        for (int tile = 0; tile < 4; ++tile) {
            bf16x8 A[4];
            #pragma unroll
            for (int kt = 0; kt < 4; ++kt)
                A[kt] = *(const bf16x8*)(xl + tile * 4096 + axoff[kt]);
            char* ss = obase + (F0c + tile * 16) * 1024;
            #pragma unroll
            for (int jj = 0; jj < 6; ++jj) {
                f32x4 acc = {bih[jj], bih[jj], bih[jj], bih[jj]};
                #pragma unroll
                for (int kt = 0; kt < 4; ++kt)
                    acc = __builtin_amdgcn_mfma_f32_16x16x32_bf16(A[kt], Wf[jj][kt], acc, 0, 0, 0);
                const int nt = (jj >> 1) * 8 + w * 2 + (jj & 1);
                uint2 u;
                u.x = pk2(acc[0], acc[1]);
                u.y = pk2(acc[2], acc[3]);
                *(uint2*)(ss + nt * 512 + lane * 8) = u;
            }
        }
        __syncthreads();
    }
}

// ---------------------------------------------------------------------------
// K2 v3: GRU scan. 256 blocks x 4 rows (all same env) x 256 thr.
// Per step: A-frags from 16-row LDS tile (rows 4-15 zero), 24 MFMAs/wave,
// gate redistribution via per-wave LDS (16 lanes write b64, all 64 read 2
// triples), rcp-based pointwise, gi prefetched in pointwise layout.
// ---------------------------------------------------------------------------
__global__ __launch_bounds__(256, 1) void k_scan(
    const float* __restrict__ h0, const float* __restrict__ masks,
    const float* __restrict__ W_hh, const float* __restrict__ b_hh,
    char* __restrict__ obase, float* __restrict__ dout)
{
    const int tid = threadIdx.x;
    const int w = tid >> 6, lane = tid & 63;
    const int lr = lane & 15, lq = lane >> 4;
    const int kk = lane & 31, mm2 = lane >> 5;   // pointwise mapping
    const int b = blockIdx.x;
    const int env = b >> 2;                      // == 16-row tile index Rt
    const int p = (b & 3) * 4;                   // within-tile row offset
    const int k = w * 32 + kk;                   // this lane's h-dim

    __shared__ __align__(16) char hbf[2 * 4096];   // [16][128] bf16 x2, swizzled
    __shared__ __align__(16) char gbuf[4 * 2304];  // per-wave gates [3][32][4] f32, 24B k-stride
    __shared__ float msk[TT];

    msk[tid] = masks[tid * 64 + env];
    // zero both h buffers (rows 4-15 stay zero forever)
    *(uint4*)(hbf + tid * 32) = uint4{0u, 0u, 0u, 0u};
    *(uint4*)(hbf + tid * 32 + 16) = uint4{0u, 0u, 0u, 0u};

    // W_hh B-frags (o-slice: g*128 + w*32 + n2*16 + lr)
    bf16x8 Wf[6][4];
    float bhh[6];
    #pragma unroll
    for (int g = 0; g < 3; ++g)
        #pragma unroll
        for (int n2 = 0; n2 < 2; ++n2) {
            const int jj = g * 2 + n2;
            const int o = g * 128 + w * 32 + n2 * 16 + lr;
            bhh[jj] = b_hh[o];
            #pragma unroll
            for (int kt = 0; kt < 4; ++kt)
                Wf[jj][kt] = ld8cvt(W_hh + (size_t)o * 128 + kt * 32 + lq * 8);
        }

    // precomputed offsets
    int roff[4];
    #pragma unroll
    for (int kt = 0; kt < 4; ++kt)
        roff[kt] = lr * 256 + ((kt * 64 + lq * 16) ^ (lr << 4));
    char* const gw = gbuf + w * 2304;
    int gioff[3];
    #pragma unroll
    for (int g = 0; g < 3; ++g)
        gioff[g] = (g * 8 + w * 2 + (kk >> 4)) * 512 + ((b & 3) * 16 + (kk & 15)) * 8 + mm2 * 4;
    const int ysoff = (k * 16 + p + 2 * mm2) * 2;
    int hwoff[2];
    #pragma unroll
    for (int i = 0; i < 2; ++i) {
        const int m = 2 * mm2 + i;
        hwoff[i] = m * 256 + ((k * 2) ^ (m << 4));
    }

    __syncthreads();                 // msk + zeros visible
    const float m0 = msk[0];

    // h state (pointwise layout): rows b*4 + 2*mm2 + {0,1}, col k
    float hold[2];
    #pragma unroll
    for (int i = 0; i < 2; ++i) {
        const int row = b * 4 + 2 * mm2 + i;
        hold[i] = h0[(size_t)row * 128 + k] * m0;
        *(uint16_t*)(hbf + hwoff[i]) = bf1(hold[i]);
    }

    // prefetch t=0 gi (3 u32 per lane, pointwise layout)
    uint32_t gic[3];
    {
        const char* gp = obase + (size_t)env * 16384;
        #pragma unroll
        for (int g = 0; g < 3; ++g)
            gic[g] = *(const uint32_t*)(gp + gioff[g]);
    }
    const char* gnext = obase + (1 << 20) + (size_t)env * 16384;
    char* ysp = obase + (size_t)env * 16384 + 12288;
    __syncthreads();                 // hbf[0] ready

#define STEP(B, T) { \
    bf16x8 A[4]; \
    _Pragma("unroll") for (int kt = 0; kt < 4; ++kt) \
        A[kt] = *(const bf16x8*)(hbf + (B) * 4096 + roff[kt]); \
    uint32_t gn[3]; float mnx; \
    if ((T) < TT - 1) { \
        _Pragma("unroll") for (int g = 0; g < 3; ++g) \
            gn[g] = *(const uint32_t*)(gnext + gioff[g]); \
        mnx = msk[(T) + 1]; \
    } else { \
        gn[0] = gn[1] = gn[2] = 0u; mnx = 1.0f; \
    } \
    f32x4 acc[6]; \
    _Pragma("unroll") for (int jj = 0; jj < 6; ++jj) { \
        f32x4 c = {bhh[jj], bhh[jj], bhh[jj], bhh[jj]}; \
        _Pragma("unroll") for (int kt = 0; kt < 4; ++kt) \
            c = __builtin_amdgcn_mfma_f32_16x16x32_bf16(A[kt], Wf[jj][kt], c, 0, 0, 0); \
        acc[jj] = c; \
    } \
    if (lq == 0) { \
        _Pragma("unroll") for (int g = 0; g < 3; ++g) \
            _Pragma("unroll") for (int n2 = 0; n2 < 2; ++n2) { \
                const int jj = g * 2 + n2; \
                char* ga = gw + g * 768 + (n2 * 16 + lr) * 24; \
                *(float2*)ga = float2{acc[jj][0], acc[jj][1]}; \
                *(float2*)(ga + 8) = float2{acc[jj][2], acc[jj][3]}; \
            } \
    } \
    __syncthreads(); \
    const float2 ghr2 = *(const float2*)(gw + 0 * 768 + kk * 24 + mm2 * 8); \
    const float2 ghz2 = *(const float2*)(gw + 1 * 768 + kk * 24 + mm2 * 8); \
    const float2 ghn2 = *(const float2*)(gw + 2 * 768 + kk * 24 + mm2 * 8); \
    float hn[2]; \
    _Pragma("unroll") for (int i = 0; i < 2; ++i) { \
        const float gir = bf2f(i ? (gic[0] >> 16) : (gic[0] & 0xffffu)); \
        const float giz = bf2f(i ? (gic[1] >> 16) : (gic[1] & 0xffffu)); \
        const float gin = bf2f(i ? (gic[2] >> 16) : (gic[2] & 0xffffu)); \
        const float ghr = i ? ghr2.y : ghr2.x; \
        const float ghz = i ? ghz2.y : ghz2.x; \
        const float ghn = i ? ghn2.y : ghn2.x; \
        const float rr = rcpf(1.f + __expf(-(gir + ghr))); \
        const float zz = rcpf(1.f + __expf(-(giz + ghz))); \
        const float pre = gin + rr * ghn; \
        const float nn = 1.f - 2.f * rcpf(__expf(2.f * pre) + 1.f); \
        hn[i] = nn + zz * (hold[i] - nn); \
    } \
    *(uint32_t*)(ysp + ysoff) = pk2(hn[0], hn[1]); \
    hold[0] = hn[0] * mnx; hold[1] = hn[1] * mnx; \
    *(uint16_t*)(hbf + ((B) ^ 1) * 4096 + hwoff[0]) = bf1(hold[0]); \
    *(uint16_t*)(hbf + ((B) ^ 1) * 4096 + hwoff[1]) = bf1(hold[1]); \
    gic[0] = gn[0]; gic[1] = gn[1]; gic[2] = gn[2]; \
    gnext += (1 << 20); ysp += (1 << 20); \
    __syncthreads(); \
}

    for (int t2 = 0; t2 < TT; t2 += 2) {
        STEP(0, t2)
        STEP(1, t2 + 1)
    }
#undef STEP

    // h_last f32 (unmasked: mnx=1 at t=255)
    #pragma unroll
    for (int i = 0; i < 2; ++i)
        dout[OUT_ELEMS + (size_t)(b * 4 + 2 * mm2 + i) * 128 + k] = hold[i];
}

// ---------------------------------------------------------------------------
// K3: out = ys@W_outT + b_out (f32, overwrites superslot).
// ---------------------------------------------------------------------------
__global__ __launch_bounds__(256, 2) void k_out(
    const float* __restrict__ W_out, const float* __restrict__ b_out,
    char* __restrict__ obase)
{
    const int tid = threadIdx.x;
    const int w = tid >> 6, lane = tid & 63;
    const int lr = lane & 15, lq = lane >> 4;

    __shared__ __align__(16) uint4 ysbuf[4][256];  // 4 x 4KB

    bf16x8 Wf[4][4];
    float bo[4];
    #pragma unroll
    for (int ntl = 0; ntl < 4; ++ntl) {
        const int o = w * 64 + ntl * 16 + lr;
        bo[ntl] = b_out[o];
        #pragma unroll
        for (int kt = 0; kt < 4; ++kt)
            Wf[ntl][kt] = ld8cvt(W_out + (size_t)o * 128 + kt * 32 + lq * 8);
    }

    for (int it = 0; it < 8; ++it) {
        const int S0 = blockIdx.x * 32 + it * 4;
        {
            const int tb = tid >> 6, li = tid & 63;
            const uint4* src = (const uint4*)(obase + (size_t)(S0 + tb) * 16384 + 12288);
            #pragma unroll
            for (int i = 0; i < 4; ++i) ysbuf[tb][li + i * 64] = src[li + i * 64];
        }
        __syncthreads();
        #pragma unroll 1
        for (int tile = 0; tile < 4; ++tile) {
            const short* yb = (const short*)ysbuf[tile];
            bf16x8 A[4];
            #pragma unroll
            for (int kt = 0; kt < 4; ++kt) {
                bf16x8 a;
                #pragma unroll
                for (int j = 0; j < 8; ++j) {
                    const int kx = kt * 32 + lq * 8 + j;
                    a[j] = yb[kx * 16 + lr];     // col-major gather, conflict-free
                }
                A[kt] = a;
            }
            char* ssp = obase + (size_t)(S0 + tile) * 16384;
            #pragma unroll
            for (int ntl = 0; ntl < 4; ++ntl) {
                f32x4 acc = {bo[ntl], bo[ntl], bo[ntl], bo[ntl]};
                #pragma unroll
                for (int kt = 0; kt < 4; ++kt)
                    acc = __builtin_amdgcn_mfma_f32_16x16x32_bf16(A[kt], Wf[ntl][kt], acc, 0, 0, 0);
                const int o = w * 64 + ntl * 16 + lr;
                #pragma unroll
                for (int r = 0; r < 4; ++r) {
                    const int m = lq * 4 + r;
                    *(float*)(ssp + m * 1024 + o * 4) = acc[r];
                }
            }
        }
        __syncthreads();
    }
}

extern "C" void kernel_launch(void* const* d_in, const int* in_sizes, int n_in,
                              void* d_out, int out_size, void* d_ws, size_t ws_size,
                              hipStream_t stream) {
    const float* pos    = (const float*)d_in[0];
    const float* ht     = (const float*)d_in[1];
    const float* hs     = (const float*)d_in[2];
    const float* h0     = (const float*)d_in[3];
    const float* masks  = (const float*)d_in[4];
    const float* W_enc  = (const float*)d_in[5];
    const float* b_enc  = (const float*)d_in[6];
    const float* W_edge = (const float*)d_in[7];
    const float* b_edge = (const float*)d_in[8];
    const float* W_ih   = (const float*)d_in[9];
    const float* b_ih   = (const float*)d_in[10];
    const float* W_hh   = (const float*)d_in[11];
    const float* b_hh   = (const float*)d_in[12];
    const float* W_out  = (const float*)d_in[13];
    const float* b_out  = (const float*)d_in[14];
    char*  obase = (char*)d_out;
    float* out   = (float*)d_out;

    hipLaunchKernelGGL(k_embed, dim3(512), dim3(256), 0, stream,
                       pos, ht, hs, W_enc, b_enc, W_edge, b_edge, obase);
    hipLaunchKernelGGL(k_gi, dim3(512), dim3(256), 0, stream,
                       W_ih, b_ih, obase);
    hipLaunchKernelGGL(k_scan, dim3(256), dim3(256), 0, stream,
                       h0, masks, W_hh, b_hh, obase, out);
    hipLaunchKernelGGL(k_out, dim3(512), dim3(256), 0, stream,
                       W_out, b_out, obase);
}